// Round 11
// baseline (471.018 us; speedup 1.0000x reference)
//
#include <hip/hip_runtime.h>
#include <hip/hip_bf16.h>
#include <stdint.h>

// ---------------- problem constants ----------------
#define DIMC  512
#define NHEAD 16
#define HDIM  32
#define NTOK  65536          // 4*128*128 tokens
#define QKVN  1536           // 3*DIMC
static constexpr float SCALE_F = 0.17677669529663687f;  // HD^-0.5

typedef __attribute__((ext_vector_type(4))) float  f32x4;
typedef __attribute__((ext_vector_type(8))) __bf16 bf16x8;

__device__ __forceinline__ uint16_t f2bf(float f) {
  union { float f; uint32_t u; } v; v.f = f;
  return (uint16_t)((v.u + 0x7FFFu + ((v.u >> 16) & 1u)) >> 16);
}

// async global->LDS, 16B/lane; LDS dest is wave-uniform base (+lane*16 by HW)
__device__ __forceinline__ void gload_lds16(const void* g, void* l) {
  __builtin_amdgcn_global_load_lds((const __attribute__((address_space(1))) void*)g,
                                   (__attribute__((address_space(3))) void*)l,
                                   16, 0, 0);
}

// ---------------------------------------------------------------------------
// fp32 -> bf16 convert (x and weights)
// ---------------------------------------------------------------------------
__global__ void cvt_f32_bf16(const float* __restrict__ src,
                             uint16_t* __restrict__ dst, int n4)
{
  int i = blockIdx.x * blockDim.x + threadIdx.x;
  const int stride = gridDim.x * blockDim.x;
  for (; i < n4; i += stride) {
    const float4 v = ((const float4*)src)[i];
    ushort4 o;
    o.x = f2bf(v.x); o.y = f2bf(v.y); o.z = f2bf(v.z); o.w = f2bf(v.w);
    ((ushort4*)dst)[i] = o;
  }
}

// ---------------------------------------------------------------------------
// 256x256 8-phase GEMM (round-6 version, best QKV result) — QKV only.
// ---------------------------------------------------------------------------
template <bool OUT_F32>
__global__ __launch_bounds__(512, 2)
void gemm256_8ph(const uint16_t* __restrict__ A,
                 const uint16_t* __restrict__ B,
                 const float* __restrict__ bias,
                 void* __restrict__ Cv,
                 int M, int N, int K, int gx)
{
  __shared__ __align__(16) char lds[131072];

  const int tid = threadIdx.x;
  const int l  = tid & 63, w = tid >> 6;
  const int wm = w >> 2,  wn = w & 3;
  const int lm = l & 15,  lq = l >> 4;

  const int nwg = gridDim.x;
  const int qq = nwg >> 3, rr = nwg & 7;
  const int xcd = blockIdx.x & 7, loc = blockIdx.x >> 3;
  const int sw = (xcd < rr ? xcd * (qq + 1) : rr * (qq + 1) + (xcd - rr) * qq) + loc;
  const long m0 = (long)(sw / gx) * 256;
  const long n0 = (long)(sw % gx) * 256;

  const int srow  = tid >> 3;
  const int scolb = (((tid & 7) ^ (srow & 7)) << 4);
  const uint16_t* Ags = A + (m0 + srow) * (long)K + (scolb >> 1);
  const uint16_t* Bgs = B + (n0 + srow) * (long)K + (scolb >> 1);
  char* ldsW = lds + (w << 10);

#define STAGE(Gs, regionOff, half, kt)                                        \
  {                                                                           \
    const uint16_t* s0_ = (Gs) + (size_t)((half) * 128) * K + (kt);           \
    gload_lds16(s0_,                  ldsW + (regionOff));                    \
    gload_lds16(s0_ + (size_t)64 * K, ldsW + (regionOff) + 8192);             \
  }

  const int colx0 = ((lq ^ (lm & 7)) << 4);
  const int aoff0 = (wm * 64 + lm) * 128 + colx0;
  const int aoff1 = (wm * 64 + lm) * 128 + (colx0 ^ 64);
  const int boff0 = (wn * 32 + lm) * 128 + colx0;
  const int boff1 = (wn * 32 + lm) * 128 + (colx0 ^ 64);

  f32x4  acc[2][2][4][2] = {};
  bf16x8 aX[4][2], aY[4][2];
  bf16x8 b0[2][2], b1[2][2];

#define RD_A(DST, OFF)                                                        \
  _Pragma("unroll") for (int i = 0; i < 4; ++i) {                             \
    DST[i][0] = *(const bf16x8*)(lds + (OFF) + aoff0 + i * 2048);             \
    DST[i][1] = *(const bf16x8*)(lds + (OFF) + aoff1 + i * 2048);             \
  }
#define RD_B(DST, OFF)                                                        \
  _Pragma("unroll") for (int j = 0; j < 2; ++j) {                             \
    DST[j][0] = *(const bf16x8*)(lds + (OFF) + boff0 + j * 2048);             \
    DST[j][1] = *(const bf16x8*)(lds + (OFF) + boff1 + j * 2048);             \
  }
#define MFMA16(AS, BS, QM, QN)                                                \
  __builtin_amdgcn_s_setprio(1);                                              \
  _Pragma("unroll") for (int kk = 0; kk < 2; ++kk)                            \
    _Pragma("unroll") for (int i = 0; i < 4; ++i)                             \
      _Pragma("unroll") for (int j = 0; j < 2; ++j)                           \
        acc[QM][QN][i][j] = __builtin_amdgcn_mfma_f32_16x16x32_bf16(          \
            AS[i][kk], BS[j][kk], acc[QM][QN][i][j], 0, 0, 0);                \
  __builtin_amdgcn_s_setprio(0);
#define VMW(N) asm volatile("s_waitcnt vmcnt(" #N ")");
#define BAR()  __builtin_amdgcn_s_barrier();

  STAGE(Ags, 0,             0, 0)
  STAGE(Bgs, 32768,         0, 0)
  STAGE(Ags, 16384,         1, 0)
  STAGE(Bgs, 49152,         1, 0)
  STAGE(Ags, 65536,         0, 64)
  STAGE(Bgs, 65536 + 32768, 0, 64)
  VMW(8) BAR()
  RD_A(aX, 0) RD_B(b0, 32768)
  VMW(4) BAR()

  for (int t2 = 0; t2 < K / 64; t2 += 2) {
    const int k1 = (t2 + 1) * 64;
    int k2 = (t2 + 2) * 64; if (k2 >= K) k2 = 0;
    int k3 = (t2 + 3) * 64; if (k3 >= K) k3 = 0;

    RD_B(b1, 49152)                 STAGE(Ags, 65536 + 16384, 1, k1)
    MFMA16(aX, b0, 0, 0)            BAR()
    RD_A(aY, 16384)                 STAGE(Bgs, 65536 + 49152, 1, k1)
    MFMA16(aX, b1, 0, 1)            BAR()
    STAGE(Ags, 0, 0, k2)
    MFMA16(aY, b0, 1, 0)            VMW(6) BAR()
    RD_A(aX, 65536) RD_B(b0, 65536 + 32768)
    STAGE(Bgs, 32768, 0, k2)
    MFMA16(aY, b1, 1, 1)            VMW(4) BAR()
    RD_B(b1, 65536 + 49152)         STAGE(Ags, 16384, 1, k2)
    MFMA16(aX, b0, 0, 0)            BAR()
    RD_A(aY, 65536 + 16384)         STAGE(Bgs, 49152, 1, k2)
    MFMA16(aX, b1, 0, 1)            BAR()
    STAGE(Ags, 65536, 0, k3)
    MFMA16(aY, b0, 1, 0)            VMW(6) BAR()
    RD_A(aX, 0) RD_B(b0, 32768)
    STAGE(Bgs, 65536 + 32768, 0, k3)
    MFMA16(aY, b1, 1, 1)            VMW(4) BAR()
  }
#undef STAGE
#undef RD_A
#undef RD_B
#undef MFMA16
#undef VMW
#undef BAR

#pragma unroll
  for (int qm = 0; qm < 2; ++qm)
#pragma unroll
  for (int qn = 0; qn < 2; ++qn)
#pragma unroll
  for (int i = 0; i < 4; ++i)
#pragma unroll
  for (int j = 0; j < 2; ++j) {
    const long m = m0 + qm * 128 + wm * 64 + i * 16 + lq * 4;
    const long n = n0 + qn * 128 + wn * 32 + j * 16 + lm;
    const float bv = bias[n];
#pragma unroll
    for (int r = 0; r < 4; ++r) {
      const float val = acc[qm][qn][i][j][r] + bv;
      if (OUT_F32) ((float*)Cv)[(m + r) * (long)N + n] = val;
      else         ((uint16_t*)Cv)[(m + r) * (long)N + n] = f2bf(val);
    }
  }
}

// ---------------------------------------------------------------------------
// FUSED attention + proj. One block per group g (64 tokens), 512 threads,
// 8 waves; wave w handles heads {2w, 2w+1}. Attention is the proven
// attn_win math (global QKV gathers, RoPE, wave softmax) but O rows go to
// LDS (Sout, XOR-swizzled) instead of global. Then a block-cooperative
// 64x512x512 proj GEMM: W staged to LDS via gload_lds16 with pre-swizzled
// source (coalesced; W is L2-resident across blocks), fp32 out + bias.
// Eliminates attn-write + proj-read (134 MB) and the standalone proj kernel
// (whose 2-round grid ran at only ~430 TF).
// LDS: Sout 64K + union{per-wave P scratch [64][64] | W k-tile 512x64} 64K
//   = 128 KiB -> 1 block/CU, 8 waves. Only __syncthreads() sync (m97-safe).
// Swizzle (unit = 16B, phys_u = u ^ (row&7)) identical to the numerically
// verified round-10 xs / round-9 B maps.
// ---------------------------------------------------------------------------
__global__ __launch_bounds__(512, 2)
void attn_proj(const uint16_t* __restrict__ QKV,   // [NTOK][1536] bf16
               const uint16_t* __restrict__ Wp,    // proj_w bf16 [512][512]
               const float* __restrict__ proj_b,   // [512] fp32
               float* __restrict__ out)            // [NTOK][512] fp32
{
  __shared__ __align__(16) __bf16 Sout[64][512];   // 64 KiB, swizzled
  __shared__ __align__(16) char   un[65536];       // Pl (attn) / Wtile (proj)

  const int tid = threadIdx.x;
  const int l  = tid & 63, w = tid >> 6;
  const int lm = l & 15,  lq = l >> 4;
  const int g = blockIdx.x;
  const int d1 = g & 1, d0 = (g >> 1) & 1;
  const int wx = (g >> 2) & 7, wy = (g >> 5) & 7, bb = g >> 8;
  const long tbase = ((long)(bb * 128 + wy * 16 + d0) * 128) + wx * 16 + d1;

  char* SoutC = (char*)&Sout[0][0];
  char* PlC   = un + w * 8192;                     // per-wave [64][64] bf16

  f32x4 invs;
#pragma unroll
  for (int i = 0; i < 4; ++i)
    invs[i] = exp2f(-1.6609640474436813f * (float)((lq & 1) * 4 + i));

  const f32x4 fzero = {0.f, 0.f, 0.f, 0.f};

  // ================= attention phase =================
  for (int hp = 0; hp < 2; ++hp) {
    const int h = w * 2 + hp;
    const int co_q = h * HDIM;
    const int co_k = DIMC + h * HDIM;
    const int co_v = 2 * DIMC + h * HDIM;

    // ---- Q/K gather + RoPE (verbatim proven) ----
    bf16x8 qf[4], kf[4];
#pragma unroll
    for (int f = 0; f < 4; ++f) {
      const int n = f * 16 + lm, iy = n >> 3, ix = n & 7;
      const float pos = (lq < 2) ? (float)iy : (float)ix;
      const long t = tbase + iy * 256 + ix * 2;
      const uint16_t* qp = QKV + t * QKVN + co_q + lq * 8;
      const uint16_t* kp = QKV + t * QKVN + co_k + lq * 8;
      {
        bf16x8 raw = *(const bf16x8*)qp, o;
#pragma unroll
        for (int i = 0; i < 4; ++i) {
          float x1 = (float)raw[2 * i], x2 = (float)raw[2 * i + 1];
          float s_, c_; __sincosf(pos * invs[i], &s_, &c_);
          o[2 * i]     = (__bf16)((x1 * c_ - x2 * s_) * SCALE_F);
          o[2 * i + 1] = (__bf16)((x1 * s_ + x2 * c_) * SCALE_F);
        }
        qf[f] = o;
      }
      {
        bf16x8 raw = *(const bf16x8*)kp, o;
#pragma unroll
        for (int i = 0; i < 4; ++i) {
          float x1 = (float)raw[2 * i], x2 = (float)raw[2 * i + 1];
          float s_, c_; __sincosf(pos * invs[i], &s_, &c_);
          o[2 * i]     = (__bf16)(x1 * c_ - x2 * s_);
          o[2 * i + 1] = (__bf16)(x1 * s_ + x2 * c_);
        }
        kf[f] = o;
      }
    }
    // ---- V gather (B-frags) ----
    bf16x8 vf[2][2];
#pragma unroll
    for (int kk = 0; kk < 2; ++kk)
#pragma unroll
      for (int n2 = 0; n2 < 2; ++n2) {
        const int nb = kk * 32 + lq * 8;
        const long tb2 = tbase + (long)(nb >> 3) * 256;
        const uint16_t* vp = QKV + co_v + n2 * 16 + lm;
        bf16x8 o;
#pragma unroll
        for (int i = 0; i < 8; ++i)
          o[i] = *(const __bf16*)(vp + (tb2 + 2 * i) * QKVN);
        vf[kk][n2] = o;
      }

    // ---- S = Q K^T ----
    f32x4 s[4][4];
#pragma unroll
    for (int mi = 0; mi < 4; ++mi)
#pragma unroll
      for (int ni = 0; ni < 4; ++ni)
        s[mi][ni] = __builtin_amdgcn_mfma_f32_16x16x32_bf16(
            qf[mi], kf[ni], fzero, 0, 0, 0);

    // ---- wave softmax ----
    float rsum[4][4];
#pragma unroll
    for (int mi = 0; mi < 4; ++mi)
#pragma unroll
      for (int r = 0; r < 4; ++r) {
        float m = s[mi][0][r];
#pragma unroll
        for (int ni = 1; ni < 4; ++ni) m = fmaxf(m, s[mi][ni][r]);
        m = fmaxf(m, __shfl_xor(m, 1));
        m = fmaxf(m, __shfl_xor(m, 2));
        m = fmaxf(m, __shfl_xor(m, 4));
        m = fmaxf(m, __shfl_xor(m, 8));
        float sum = 0.f;
#pragma unroll
        for (int ni = 0; ni < 4; ++ni) {
          float p = expf(s[mi][ni][r] - m);
          s[mi][ni][r] = p;
          sum += p;
        }
        sum += __shfl_xor(sum, 1);
        sum += __shfl_xor(sum, 2);
        sum += __shfl_xor(sum, 4);
        sum += __shfl_xor(sum, 8);
        rsum[mi][r] = sum;
      }

    // ---- P -> per-wave LDS scratch (swizzled [64][64]) ----
#pragma unroll
    for (int mi = 0; mi < 4; ++mi)
#pragma unroll
      for (int ni = 0; ni < 4; ++ni)
#pragma unroll
        for (int r = 0; r < 4; ++r) {
          const int row = mi * 16 + lq * 4 + r;
          const int u   = ni * 2 + (lm >> 3);
          *(__bf16*)(PlC + row * 128 + ((u ^ (row & 7)) << 4) + (lm & 7) * 2)
              = (__bf16)s[mi][ni][r];
        }
    bf16x8 pa[4][2];
#pragma unroll
    for (int mi = 0; mi < 4; ++mi)
#pragma unroll
      for (int kk = 0; kk < 2; ++kk)
        pa[mi][kk] = *(const bf16x8*)(PlC + (mi * 16 + lm) * 128 +
                                      (((kk * 4 + lq) ^ (lm & 7)) << 4));

    // ---- O = P V ----
    f32x4 oacc[4][2] = {};
#pragma unroll
    for (int kk = 0; kk < 2; ++kk)
#pragma unroll
      for (int mi = 0; mi < 4; ++mi)
#pragma unroll
        for (int n2 = 0; n2 < 2; ++n2)
          oacc[mi][n2] = __builtin_amdgcn_mfma_f32_16x16x32_bf16(
              pa[mi][kk], vf[kk][n2], oacc[mi][n2], 0, 0, 0);

    // ---- normalize + write O rows into Sout (swizzled) ----
#pragma unroll
    for (int mi = 0; mi < 4; ++mi)
#pragma unroll
      for (int r = 0; r < 4; ++r) {
        const int n = mi * 16 + lq * 4 + r;
        const float rinv = 1.0f / rsum[mi][r];
#pragma unroll
        for (int n2 = 0; n2 < 2; ++n2) {
          const int u = h * 4 + n2 * 2 + (lm >> 3);
          *(__bf16*)(SoutC + n * 1024 + ((u ^ (n & 7)) << 4) + (lm & 7) * 2)
              = (__bf16)(oacc[mi][n2][r] * rinv);
        }
      }
  }
  __syncthreads();   // all heads' O rows published; Pl region free for Wtile

  // ================= proj phase: out[64][512] = Sout @ Wp^T + b =================
  const int sr = w * 8 + (l >> 3);                 // staging row within 64-group
  const int su = (l & 7) ^ ((l >> 3) & 7);         // pre-swizzled source unit
  char* unW = un + (w << 10);

  f32x4 acc[4][4] = {};
  for (int kt = 0; kt < 8; ++kt) {
    // stage W k-tile: 512 rows x 64 k (64 KiB)
#pragma unroll
    for (int c = 0; c < 8; ++c)
      gload_lds16(Wp + (size_t)(c * 64 + sr) * DIMC + kt * 64 + su * 8,
                  unW + c * 8192);
    __syncthreads();   // staged (compiler drains vmcnt at barrier)

#pragma unroll
    for (int kk = 0; kk < 2; ++kk) {
      bf16x8 a[4], b[4];
#pragma unroll
      for (int i = 0; i < 4; ++i)
        a[i] = *(const bf16x8*)(SoutC + (i * 16 + lm) * 1024 +
                                ((kt * 8 + ((kk * 4 + lq) ^ (lm & 7))) << 4));
#pragma unroll
      for (int j = 0; j < 4; ++j)
        b[j] = *(const bf16x8*)(un + (w * 64 + j * 16 + lm) * 128 +
                                (((kk * 4 + lq) ^ (lm & 7)) << 4));
#pragma unroll
      for (int i = 0; i < 4; ++i)
#pragma unroll
        for (int j = 0; j < 4; ++j)
          acc[i][j] = __builtin_amdgcn_mfma_f32_16x16x32_bf16(
              a[i], b[j], acc[i][j], 0, 0, 0);
    }
    __syncthreads();   // Wtile reads done before next stage
  }

  // epilogue: out-dim o = w*64 + j*16 + lm; token n = i*16 + lq*4 + r
#pragma unroll
  for (int i = 0; i < 4; ++i)
#pragma unroll
    for (int j = 0; j < 4; ++j) {
      const int o = w * 64 + j * 16 + lm;
      const float bv = proj_b[o];
#pragma unroll
      for (int r = 0; r < 4; ++r) {
        const int n = i * 16 + lq * 4 + r;
        const long t = tbase + (n >> 3) * 256 + (n & 7) * 2;
        out[t * DIMC + o] = acc[i][j][r] + bv;
      }
    }
}

// ---------------------------------------------------------------------------
extern "C" void kernel_launch(void* const* d_in, const int* in_sizes, int n_in,
                              void* d_out, int out_size, void* d_ws, size_t ws_size,
                              hipStream_t stream)
{
  const float* x      = (const float*)d_in[0];   // [65536][512] fp32
  const float* qkv_w  = (const float*)d_in[1];   // [1536][512]  fp32
  const float* qkv_b  = (const float*)d_in[2];   // [1536]       fp32
  const float* proj_w = (const float*)d_in[3];   // [512][512]   fp32
  const float* proj_b = (const float*)d_in[4];   // [512]        fp32
  float* out = (float*)d_out;                    // [65536][512] fp32

  uint16_t* xb   = (uint16_t*)d_ws;                      // 64 MiB
  uint16_t* qwb  = xb  + (size_t)NTOK * DIMC;            // 1.5 MiB
  uint16_t* pwb  = qwb + (size_t)QKVN * DIMC;            // 0.5 MiB
  uint16_t* qkv  = pwb + (size_t)DIMC * DIMC;            // 192 MiB

  // 0) fp32 -> bf16 conversions
  cvt_f32_bf16<<<2048, 256, 0, stream>>>(x,      xb,  NTOK * DIMC / 4);
  cvt_f32_bf16<<<512,  256, 0, stream>>>(qkv_w,  qwb, QKVN * DIMC / 4);
  cvt_f32_bf16<<<256,  256, 0, stream>>>(proj_w, pwb, DIMC * DIMC / 4);

  // 1) QKV = x @ qkv_w^T + qkv_b  (bf16 out)
  gemm256_8ph<false><<<dim3((NTOK / 256) * (QKVN / 256)), dim3(512), 0, stream>>>(
      xb, qwb, qkv_b, qkv, NTOK, QKVN, DIMC, QKVN / 256);

  // 2) fused attention + proj (1024 groups; writes fp32 out directly)
  attn_proj<<<dim3(1024), dim3(512), 0, stream>>>(qkv, pwb, proj_b, out);
}

// Round 12
// 337.019 us; speedup vs baseline: 1.3976x; 1.3976x over previous
//
#include <hip/hip_runtime.h>
#include <hip/hip_bf16.h>
#include <stdint.h>

// ---------------- problem constants ----------------
#define DIMC  512
#define NHEAD 16
#define HDIM  32
#define NTOK  65536          // 4*128*128 tokens
#define QKVN  1536           // 3*DIMC
static constexpr float SCALE_F = 0.17677669529663687f;  // HD^-0.5

typedef __attribute__((ext_vector_type(4))) float  f32x4;
typedef __attribute__((ext_vector_type(8))) __bf16 bf16x8;

__device__ __forceinline__ uint16_t f2bf(float f) {
  union { float f; uint32_t u; } v; v.f = f;
  return (uint16_t)((v.u + 0x7FFFu + ((v.u >> 16) & 1u)) >> 16);
}

// async global->LDS, 16B/lane; LDS dest is wave-uniform base (+lane*16 by HW)
__device__ __forceinline__ void gload_lds16(const void* g, void* l) {
  __builtin_amdgcn_global_load_lds((const __attribute__((address_space(1))) void*)g,
                                   (__attribute__((address_space(3))) void*)l,
                                   16, 0, 0);
}

// ---------------------------------------------------------------------------
// weights fp32 -> bf16 (single launch for both weight tensors)
// ---------------------------------------------------------------------------
__global__ void cvt_weights(const float* __restrict__ qw,
                            const float* __restrict__ pw,
                            uint16_t* __restrict__ qd,
                            uint16_t* __restrict__ pd)
{
  const int n4q = QKVN * DIMC / 4;            // 196608
  const int n4t = n4q + DIMC * DIMC / 4;      // 262144
  int i = blockIdx.x * blockDim.x + threadIdx.x;
  const int stride = gridDim.x * blockDim.x;
  for (; i < n4t; i += stride) {
    const float4 v = (i < n4q) ? ((const float4*)qw)[i] : ((const float4*)pw)[i - n4q];
    ushort4 o;
    o.x = f2bf(v.x); o.y = f2bf(v.y); o.z = f2bf(v.z); o.w = f2bf(v.w);
    if (i < n4q) ((ushort4*)qd)[i] = o; else ((ushort4*)pd)[i - n4q] = o;
  }
}

// ---------------------------------------------------------------------------
// QKV GEMM: 256x256 8-phase (round-6 schedule) with FUSED fp32->bf16 A-path.
// A is x (fp32): A-staging replaced by {asm global_load_dwordx4 issued 2
// phases early (T14) -> cvt -> linear ds_write_b128} producing the SAME LDS
// bytes at the SAME phases as the old gload_lds16. All A loads are asm
// volatile (pinned issue order); guards are explicit.
// vmcnt ledger (loads; A-issue = 4, B-stage = 2; steady entry at p0 = 6
// outstanding: pfA(4) + B@p7'(2)):
//   p0: VMW(2) completes pfA            -> W(s1.A1); issue pfB(s0.A0,k2)
//   p1: B(s1.B1,k1)
//   p2: VMW(2) completes B@p7'+pfB      -> W(s0.A0); issue pfA(s0.A1,k2)
//        [B@p7' = s1.B0, read at p3 -> guarded here, one phase early]
//   p3: B(s0.B0,k2); VMW(6) completes B@p1=s1.B1 (read at p4)
//   p4: VMW(2) completes pfA            -> W(s0.A1); issue pfB(s1.A0,k3)
//   p5: B(s0.B1,k2)
//   p6: VMW(2) completes B@p3+pfB       -> W(s1.A0); issue pfA(s1.A1,k3)
//        [B@p3 = s0.B0, read at p7 -> guarded]
//   p7: B(s1.B0,k3); VMW(6) completes B@p5=s0.B1 (read at p0')
// Exit of each phase leaves 6 or 8 outstanding, never drains to 0.
// Region overwrite safety unchanged from round 6 (>=2 barriers read->write;
// ds_write lands earlier than DMA did -> strictly safer for readers).
// sched_barrier(0) after each guard wait: stops VALU/ds ops hoisting past
// the asm waitcnt (rule #18).
// ---------------------------------------------------------------------------
__global__ __launch_bounds__(512, 2)
void gemm256_qkv(const float* __restrict__ A,       // x fp32 [M][K]
                 const uint16_t* __restrict__ B,    // qkv_w bf16 [N][K]
                 const float* __restrict__ bias,
                 uint16_t* __restrict__ C,          // bf16 [M][N]
                 int M, int N, int K, int gx)
{
  __shared__ __align__(16) char lds[131072];

  const int tid = threadIdx.x;
  const int l  = tid & 63, w = tid >> 6;
  const int wm = w >> 2,  wn = w & 3;
  const int lm = l & 15,  lq = l >> 4;

  const int nwg = gridDim.x;
  const int qq = nwg >> 3, rr = nwg & 7;
  const int xcd = blockIdx.x & 7, loc = blockIdx.x >> 3;
  const int sw = (xcd < rr ? xcd * (qq + 1) : rr * (qq + 1) + (xcd - rr) * qq) + loc;
  const long m0 = (long)(sw / gx) * 256;
  const long n0 = (long)(sw % gx) * 256;

  const int srow = tid >> 3;
  const int sux  = (tid & 7) ^ (srow & 7);          // pre-swizzled 16B unit
  const uint16_t* Bgs = B + (n0 + srow) * (long)K + sux * 8;
  const float*    Agf = A + (m0 + srow) * (long)K + sux * 8;
  char* ldsW = lds + (w << 10);

#define STAGEB(regionOff, half, kt)                                           \
  {                                                                           \
    const uint16_t* s0_ = Bgs + (size_t)((half) * 128) * K + (kt);            \
    gload_lds16(s0_,                  ldsW + (regionOff));                    \
    gload_lds16(s0_ + (size_t)64 * K, ldsW + (regionOff) + 8192);             \
  }
#define A_ISSUE(SET, half, kt)                                                \
  {                                                                           \
    const float* ap_ = Agf + (size_t)((half) * 128) * K + (kt);               \
    const float* aq_ = ap_ + (size_t)64 * K;                                  \
    asm volatile("global_load_dwordx4 %0, %1, off" : "=&v"(SET[0]) : "v"(ap_));     \
    asm volatile("global_load_dwordx4 %0, %1, off" : "=&v"(SET[1]) : "v"(ap_ + 4)); \
    asm volatile("global_load_dwordx4 %0, %1, off" : "=&v"(SET[2]) : "v"(aq_));     \
    asm volatile("global_load_dwordx4 %0, %1, off" : "=&v"(SET[3]) : "v"(aq_ + 4)); \
  }
#define A_WRITE(SET, regionOff)                                               \
  {                                                                           \
    bf16x8 v0_, v1_;                                                          \
    _Pragma("unroll") for (int q_ = 0; q_ < 4; ++q_) {                        \
      v0_[q_] = (__bf16)SET[0][q_]; v0_[q_ + 4] = (__bf16)SET[1][q_];         \
      v1_[q_] = (__bf16)SET[2][q_]; v1_[q_ + 4] = (__bf16)SET[3][q_];         \
    }                                                                         \
    *(bf16x8*)(lds + (regionOff) + tid * 16) = v0_;                           \
    *(bf16x8*)(lds + (regionOff) + 8192 + tid * 16) = v1_;                    \
  }

  const int colx0 = ((lq ^ (lm & 7)) << 4);
  const int aoff0 = (wm * 64 + lm) * 128 + colx0;
  const int aoff1 = (wm * 64 + lm) * 128 + (colx0 ^ 64);
  const int boff0 = (wn * 32 + lm) * 128 + colx0;
  const int boff1 = (wn * 32 + lm) * 128 + (colx0 ^ 64);

  f32x4  acc[2][2][4][2] = {};
  bf16x8 aX[4][2], aY[4][2];
  bf16x8 b0[2][2], b1[2][2];
  f32x4  pfA[4], pfB[4];

#define RD_A(DST, OFF)                                                        \
  _Pragma("unroll") for (int i = 0; i < 4; ++i) {                             \
    DST[i][0] = *(const bf16x8*)(lds + (OFF) + aoff0 + i * 2048);             \
    DST[i][1] = *(const bf16x8*)(lds + (OFF) + aoff1 + i * 2048);             \
  }
#define RD_B(DST, OFF)                                                        \
  _Pragma("unroll") for (int j = 0; j < 2; ++j) {                             \
    DST[j][0] = *(const bf16x8*)(lds + (OFF) + boff0 + j * 2048);             \
    DST[j][1] = *(const bf16x8*)(lds + (OFF) + boff1 + j * 2048);             \
  }
#define MFMA16(AS, BS, QM, QN)                                                \
  __builtin_amdgcn_s_setprio(1);                                              \
  _Pragma("unroll") for (int kk = 0; kk < 2; ++kk)                            \
    _Pragma("unroll") for (int i = 0; i < 4; ++i)                             \
      _Pragma("unroll") for (int j = 0; j < 2; ++j)                           \
        acc[QM][QN][i][j] = __builtin_amdgcn_mfma_f32_16x16x32_bf16(          \
            AS[i][kk], BS[j][kk], acc[QM][QN][i][j], 0, 0, 0);                \
  __builtin_amdgcn_s_setprio(0);
#define VMW(N) asm volatile("s_waitcnt vmcnt(" #N ")");
#define SB()   __builtin_amdgcn_sched_barrier(0);
#define BAR()  __builtin_amdgcn_s_barrier();

  // LDS regions: s0.A0=0 s0.A1=16384 s0.B0=32768 s0.B1=49152; s1 = +65536
  // ---- prologue: build steady-state entry (pfA(4)+s1.B0(2) outstanding) ----
  A_ISSUE(pfB, 0, 0)                 // s0.A0
  STAGEB(32768, 0, 0)                // s0.B0
  STAGEB(49152, 1, 0)                // s0.B1
  VMW(0) SB()
  A_WRITE(pfB, 0)
  A_ISSUE(pfB, 1, 0)                 // s0.A1
  VMW(0) SB()
  A_WRITE(pfB, 16384)
  A_ISSUE(pfB, 0, 64)                // s1.A0
  VMW(0) SB()
  A_WRITE(pfB, 65536)
  A_ISSUE(pfA, 1, 64)                // s1.A1 @ k1=64 (written at loop p0)
  STAGEB(65536 + 32768, 0, 64)       // s1.B0 (younger than pfA -> steady state)
  BAR()
  RD_A(aX, 0) RD_B(b0, 32768)        // warm first-phase fragments

  for (int t2 = 0; t2 < K / 64; t2 += 2) {
    const int k1 = (t2 + 1) * 64;
    int k2 = (t2 + 2) * 64; if (k2 >= K) k2 = 0;   // clamped: staged, never read
    int k3 = (t2 + 3) * 64; if (k3 >= K) k3 = 0;

    // p0
    RD_B(b1, 49152)
    VMW(2) SB() A_WRITE(pfA, 65536 + 16384) A_ISSUE(pfB, 0, k2)
    MFMA16(aX, b0, 0, 0)  BAR()
    // p1
    RD_A(aY, 16384)
    STAGEB(65536 + 49152, 1, k1)
    MFMA16(aX, b1, 0, 1)  BAR()
    // p2
    VMW(2) SB() A_WRITE(pfB, 0) A_ISSUE(pfA, 1, k2)
    MFMA16(aY, b0, 1, 0)  BAR()
    // p3
    RD_A(aX, 65536) RD_B(b0, 65536 + 32768)
    STAGEB(32768, 0, k2)
    MFMA16(aY, b1, 1, 1)  VMW(6) BAR()
    // p4
    RD_B(b1, 65536 + 49152)
    VMW(2) SB() A_WRITE(pfA, 16384) A_ISSUE(pfB, 0, k3)
    MFMA16(aX, b0, 0, 0)  BAR()
    // p5
    RD_A(aY, 65536 + 16384)
    STAGEB(49152, 1, k2)
    MFMA16(aX, b1, 0, 1)  BAR()
    // p6
    VMW(2) SB() A_WRITE(pfB, 65536) A_ISSUE(pfA, 1, k3)
    MFMA16(aY, b0, 1, 0)  BAR()
    // p7
    RD_A(aX, 0) RD_B(b0, 32768)
    STAGEB(65536 + 32768, 0, k3)
    MFMA16(aY, b1, 1, 1)  VMW(6) BAR()
  }
#undef STAGEB
#undef A_ISSUE
#undef A_WRITE
#undef RD_A
#undef RD_B
#undef MFMA16
#undef VMW
#undef SB
#undef BAR

  // epilogue: C/D layout col = l&15, row = (l>>4)*4 + r
#pragma unroll
  for (int qm = 0; qm < 2; ++qm)
#pragma unroll
  for (int qn = 0; qn < 2; ++qn)
#pragma unroll
  for (int i = 0; i < 4; ++i)
#pragma unroll
  for (int j = 0; j < 2; ++j) {
    const long m = m0 + qm * 128 + wm * 64 + i * 16 + lq * 4;
    const long n = n0 + qn * 128 + wn * 32 + j * 16 + lm;
    const float bv = bias[n];
#pragma unroll
    for (int r = 0; r < 4; ++r)
      C[(m + r) * (long)N + n] = f2bf(acc[qm][qn][i][j][r] + bv);
  }
}

// ---------------------------------------------------------------------------
// 256x256 8-phase GEMM (round-6 version, unchanged) — proj only.
// ---------------------------------------------------------------------------
template <bool OUT_F32>
__global__ __launch_bounds__(512, 2)
void gemm256_8ph(const uint16_t* __restrict__ A,
                 const uint16_t* __restrict__ B,
                 const float* __restrict__ bias,
                 void* __restrict__ Cv,
                 int M, int N, int K, int gx)
{
  __shared__ __align__(16) char lds[131072];

  const int tid = threadIdx.x;
  const int l  = tid & 63, w = tid >> 6;
  const int wm = w >> 2,  wn = w & 3;
  const int lm = l & 15,  lq = l >> 4;

  const int nwg = gridDim.x;
  const int qq = nwg >> 3, rr = nwg & 7;
  const int xcd = blockIdx.x & 7, loc = blockIdx.x >> 3;
  const int sw = (xcd < rr ? xcd * (qq + 1) : rr * (qq + 1) + (xcd - rr) * qq) + loc;
  const long m0 = (long)(sw / gx) * 256;
  const long n0 = (long)(sw % gx) * 256;

  const int srow  = tid >> 3;
  const int scolb = (((tid & 7) ^ (srow & 7)) << 4);
  const uint16_t* Ags = A + (m0 + srow) * (long)K + (scolb >> 1);
  const uint16_t* Bgs = B + (n0 + srow) * (long)K + (scolb >> 1);
  char* ldsW = lds + (w << 10);

#define STAGE(Gs, regionOff, half, kt)                                        \
  {                                                                           \
    const uint16_t* s0_ = (Gs) + (size_t)((half) * 128) * K + (kt);           \
    gload_lds16(s0_,                  ldsW + (regionOff));                    \
    gload_lds16(s0_ + (size_t)64 * K, ldsW + (regionOff) + 8192);             \
  }

  const int colx0 = ((lq ^ (lm & 7)) << 4);
  const int aoff0 = (wm * 64 + lm) * 128 + colx0;
  const int aoff1 = (wm * 64 + lm) * 128 + (colx0 ^ 64);
  const int boff0 = (wn * 32 + lm) * 128 + colx0;
  const int boff1 = (wn * 32 + lm) * 128 + (colx0 ^ 64);

  f32x4  acc[2][2][4][2] = {};
  bf16x8 aX[4][2], aY[4][2];
  bf16x8 b0[2][2], b1[2][2];

#define RD_A(DST, OFF)                                                        \
  _Pragma("unroll") for (int i = 0; i < 4; ++i) {                             \
    DST[i][0] = *(const bf16x8*)(lds + (OFF) + aoff0 + i * 2048);             \
    DST[i][1] = *(const bf16x8*)(lds + (OFF) + aoff1 + i * 2048);             \
  }
#define RD_B(DST, OFF)                                                        \
  _Pragma("unroll") for (int j = 0; j < 2; ++j) {                             \
    DST[j][0] = *(const bf16x8*)(lds + (OFF) + boff0 + j * 2048);             \
    DST[j][1] = *(const bf16x8*)(lds + (OFF) + boff1 + j * 2048);             \
  }
#define MFMA16(AS, BS, QM, QN)                                                \
  __builtin_amdgcn_s_setprio(1);                                              \
  _Pragma("unroll") for (int kk = 0; kk < 2; ++kk)                            \
    _Pragma("unroll") for (int i = 0; i < 4; ++i)                             \
      _Pragma("unroll") for (int j = 0; j < 2; ++j)                           \
        acc[QM][QN][i][j] = __builtin_amdgcn_mfma_f32_16x16x32_bf16(          \
            AS[i][kk], BS[j][kk], acc[QM][QN][i][j], 0, 0, 0);                \
  __builtin_amdgcn_s_setprio(0);
#define VMW(N) asm volatile("s_waitcnt vmcnt(" #N ")");
#define BAR()  __builtin_amdgcn_s_barrier();

  STAGE(Ags, 0,             0, 0)
  STAGE(Bgs, 32768,         0, 0)
  STAGE(Ags, 16384,         1, 0)
  STAGE(Bgs, 49152,         1, 0)
  STAGE(Ags, 65536,         0, 64)
  STAGE(Bgs, 65536 + 32768, 0, 64)
  VMW(8) BAR()
  RD_A(aX, 0) RD_B(b0, 32768)
  VMW(4) BAR()

  for (int t2 = 0; t2 < K / 64; t2 += 2) {
    const int k1 = (t2 + 1) * 64;
    int k2 = (t2 + 2) * 64; if (k2 >= K) k2 = 0;
    int k3 = (t2 + 3) * 64; if (k3 >= K) k3 = 0;

    RD_B(b1, 49152)                 STAGE(Ags, 65536 + 16384, 1, k1)
    MFMA16(aX, b0, 0, 0)            BAR()
    RD_A(aY, 16384)                 STAGE(Bgs, 65536 + 49152, 1, k1)
    MFMA16(aX, b1, 0, 1)            BAR()
    STAGE(Ags, 0, 0, k2)
    MFMA16(aY, b0, 1, 0)            VMW(6) BAR()
    RD_A(aX, 65536) RD_B(b0, 65536 + 32768)
    STAGE(Bgs, 32768, 0, k2)
    MFMA16(aY, b1, 1, 1)            VMW(4) BAR()
    RD_B(b1, 65536 + 49152)         STAGE(Ags, 16384, 1, k2)
    MFMA16(aX, b0, 0, 0)            BAR()
    RD_A(aY, 65536 + 16384)         STAGE(Bgs, 49152, 1, k2)
    MFMA16(aX, b1, 0, 1)            BAR()
    STAGE(Ags, 65536, 0, k3)
    MFMA16(aY, b0, 1, 0)            VMW(6) BAR()
    RD_A(aX, 0) RD_B(b0, 32768)
    STAGE(Bgs, 65536 + 32768, 0, k3)
    MFMA16(aY, b1, 1, 1)            VMW(4) BAR()
  }
#undef STAGE
#undef RD_A
#undef RD_B
#undef MFMA16
#undef VMW
#undef BAR

#pragma unroll
  for (int qm = 0; qm < 2; ++qm)
#pragma unroll
  for (int qn = 0; qn < 2; ++qn)
#pragma unroll
  for (int i = 0; i < 4; ++i)
#pragma unroll
  for (int j = 0; j < 2; ++j) {
    const long m = m0 + qm * 128 + wm * 64 + i * 16 + lq * 4;
    const long n = n0 + qn * 128 + wn * 32 + j * 16 + lm;
    const float bv = bias[n];
#pragma unroll
    for (int r = 0; r < 4; ++r) {
      const float val = acc[qm][qn][i][j][r] + bv;
      if (OUT_F32) ((float*)Cv)[(m + r) * (long)N + n] = val;
      else         ((uint16_t*)Cv)[(m + r) * (long)N + n] = f2bf(val);
    }
  }
}

// ---------------------------------------------------------------------------
// Windowed dilated attention (round-6 verbatim): one wave per (group, head).
// ---------------------------------------------------------------------------
__global__ void attn_win(const uint16_t* __restrict__ QKV,  // [NTOK][1536] bf16
                         uint16_t* __restrict__ O)          // [NTOK][512]  bf16
{
  __shared__ __align__(16) __bf16 Pl[4][64][72];

  const int tid = threadIdx.x;
  const int l  = tid & 63, w = tid >> 6;
  const int lm = l & 15,  lq = l >> 4;
  const int bid = blockIdx.x;
  const int g = bid >> 2;
  const int h = (bid & 3) * 4 + w;

  const int d1 = g & 1, d0 = (g >> 1) & 1;
  const int wx = (g >> 2) & 7, wy = (g >> 5) & 7, bb = g >> 8;
  const long tbase = ((long)(bb * 128 + wy * 16 + d0) * 128) + wx * 16 + d1;

  f32x4 invs;
#pragma unroll
  for (int i = 0; i < 4; ++i)
    invs[i] = exp2f(-1.6609640474436813f * (float)((lq & 1) * 4 + i));

  const int co_q = h * HDIM;
  const int co_k = DIMC + h * HDIM;
  const int co_v = 2 * DIMC + h * HDIM;

  bf16x8 qf[4], kf[4];
#pragma unroll
  for (int f = 0; f < 4; ++f) {
    const int n  = f * 16 + lm;
    const int iy = n >> 3, ix = n & 7;
    const float pos = (lq < 2) ? (float)iy : (float)ix;
    const long t = tbase + iy * 256 + ix * 2;
    const uint16_t* qp = QKV + t * QKVN + co_q + lq * 8;
    const uint16_t* kp = QKV + t * QKVN + co_k + lq * 8;
    {
      bf16x8 raw = *(const bf16x8*)qp, o;
#pragma unroll
      for (int i = 0; i < 4; ++i) {
        float x1 = (float)raw[2 * i], x2 = (float)raw[2 * i + 1];
        float s, c; __sincosf(pos * invs[i], &s, &c);
        o[2 * i]     = (__bf16)((x1 * c - x2 * s) * SCALE_F);
        o[2 * i + 1] = (__bf16)((x1 * s + x2 * c) * SCALE_F);
      }
      qf[f] = o;
    }
    {
      bf16x8 raw = *(const bf16x8*)kp, o;
#pragma unroll
      for (int i = 0; i < 4; ++i) {
        float x1 = (float)raw[2 * i], x2 = (float)raw[2 * i + 1];
        float s, c; __sincosf(pos * invs[i], &s, &c);
        o[2 * i]     = (__bf16)(x1 * c - x2 * s);
        o[2 * i + 1] = (__bf16)(x1 * s + x2 * c);
      }
      kf[f] = o;
    }
  }

  const f32x4 fzero = {0.f, 0.f, 0.f, 0.f};
  f32x4 s[4][4];
#pragma unroll
  for (int mi = 0; mi < 4; ++mi)
#pragma unroll
    for (int ni = 0; ni < 4; ++ni)
      s[mi][ni] = __builtin_amdgcn_mfma_f32_16x16x32_bf16(qf[mi], kf[ni], fzero, 0, 0, 0);

  float rsum[4][4];
#pragma unroll
  for (int mi = 0; mi < 4; ++mi)
#pragma unroll
    for (int r = 0; r < 4; ++r) {
      float m = s[mi][0][r];
#pragma unroll
      for (int ni = 1; ni < 4; ++ni) m = fmaxf(m, s[mi][ni][r]);
      m = fmaxf(m, __shfl_xor(m, 1));
      m = fmaxf(m, __shfl_xor(m, 2));
      m = fmaxf(m, __shfl_xor(m, 4));
      m = fmaxf(m, __shfl_xor(m, 8));
      float sum = 0.f;
#pragma unroll
      for (int ni = 0; ni < 4; ++ni) {
        float p = expf(s[mi][ni][r] - m);
        s[mi][ni][r] = p;
        sum += p;
      }
      sum += __shfl_xor(sum, 1);
      sum += __shfl_xor(sum, 2);
      sum += __shfl_xor(sum, 4);
      sum += __shfl_xor(sum, 8);
      rsum[mi][r] = sum;
    }

#pragma unroll
  for (int mi = 0; mi < 4; ++mi)
#pragma unroll
    for (int ni = 0; ni < 4; ++ni)
#pragma unroll
      for (int r = 0; r < 4; ++r)
        Pl[w][mi * 16 + lq * 4 + r][ni * 16 + lm] = (__bf16)s[mi][ni][r];

  bf16x8 pa[4][2];
#pragma unroll
  for (int mi = 0; mi < 4; ++mi)
#pragma unroll
    for (int kk = 0; kk < 2; ++kk)
      pa[mi][kk] = *(const bf16x8*)(&Pl[w][mi * 16 + lm][kk * 32 + lq * 8]);

  bf16x8 vf[2][2];
#pragma unroll
  for (int kk = 0; kk < 2; ++kk)
#pragma unroll
    for (int n2 = 0; n2 < 2; ++n2) {
      const int nb = kk * 32 + lq * 8;
      const long tb2 = tbase + (long)(nb >> 3) * 256;
      const uint16_t* vp = QKV + co_v + n2 * 16 + lm;
      bf16x8 o;
#pragma unroll
      for (int i = 0; i < 8; ++i)
        o[i] = *(const __bf16*)(vp + (tb2 + 2 * i) * QKVN);
      vf[kk][n2] = o;
    }

  f32x4 oacc[4][2] = {};
#pragma unroll
  for (int kk = 0; kk < 2; ++kk)
#pragma unroll
    for (int mi = 0; mi < 4; ++mi)
#pragma unroll
      for (int n2 = 0; n2 < 2; ++n2)
        oacc[mi][n2] = __builtin_amdgcn_mfma_f32_16x16x32_bf16(
            pa[mi][kk], vf[kk][n2], oacc[mi][n2], 0, 0, 0);

#pragma unroll
  for (int mi = 0; mi < 4; ++mi)
#pragma unroll
    for (int r = 0; r < 4; ++r) {
      const int n = mi * 16 + lq * 4 + r;
      const long t = tbase + (n >> 3) * 256 + (n & 7) * 2;
      const float rinv = 1.0f / rsum[mi][r];
#pragma unroll
      for (int n2 = 0; n2 < 2; ++n2)
        O[t * DIMC + h * HDIM + n2 * 16 + lm] = f2bf(oacc[mi][n2][r] * rinv);
    }
}

// ---------------------------------------------------------------------------
extern "C" void kernel_launch(void* const* d_in, const int* in_sizes, int n_in,
                              void* d_out, int out_size, void* d_ws, size_t ws_size,
                              hipStream_t stream)
{
  const float* x      = (const float*)d_in[0];   // [65536][512] fp32
  const float* qkv_w  = (const float*)d_in[1];   // [1536][512]  fp32
  const float* qkv_b  = (const float*)d_in[2];   // [1536]       fp32
  const float* proj_w = (const float*)d_in[3];   // [512][512]   fp32
  const float* proj_b = (const float*)d_in[4];   // [512]        fp32
  float* out = (float*)d_out;                    // [65536][512] fp32

  uint16_t* qwb  = (uint16_t*)d_ws;                      // 1.5 MiB
  uint16_t* pwb  = qwb + (size_t)QKVN * DIMC;            // 0.5 MiB
  uint16_t* qkv  = pwb + (size_t)DIMC * DIMC;            // 192 MiB
  uint16_t* attn = qkv + (size_t)NTOK * QKVN;            // 64 MiB

  // 0) weights fp32 -> bf16 (one launch)
  cvt_weights<<<768, 256, 0, stream>>>(qkv_w, proj_w, qwb, pwb);

  // 1) QKV = x @ qkv_w^T + qkv_b  (fp32 A fused cvt, bf16 out)
  gemm256_qkv<<<dim3((NTOK / 256) * (QKVN / 256)), dim3(512), 0, stream>>>(
      x, qwb, qkv_b, qkv, NTOK, QKVN, DIMC, QKVN / 256);

  // 2) windowed dilated attention with fused RoPE
  attn_win<<<dim3(1024 * 4), dim3(256), 0, stream>>>(qkv, attn);

  // 3) out = attn @ proj_w^T + proj_b  (fp32 out)
  gemm256_8ph<true><<<dim3((NTOK / 256) * (DIMC / 256)), dim3(512), 0, stream>>>(
      attn, pwb, proj_b, out, NTOK, DIMC, DIMC, DIMC / 256);
}

// Round 13
// 299.253 us; speedup vs baseline: 1.5740x; 1.1262x over previous
//
#include <hip/hip_runtime.h>
#include <hip/hip_bf16.h>
#include <stdint.h>

// ---------------- problem constants ----------------
#define DIMC  512
#define NHEAD 16
#define HDIM  32
#define NTOK  65536          // 4*128*128 tokens
#define QKVN  1536           // 3*DIMC
static constexpr float SCALE_F = 0.17677669529663687f;  // HD^-0.5

typedef __attribute__((ext_vector_type(4))) float  f32x4;
typedef __attribute__((ext_vector_type(8))) __bf16 bf16x8;

__device__ __forceinline__ uint16_t f2bf(float f) {
  union { float f; uint32_t u; } v; v.f = f;
  return (uint16_t)((v.u + 0x7FFFu + ((v.u >> 16) & 1u)) >> 16);
}

// async global->LDS, 16B/lane; LDS dest is wave-uniform base (+lane*16 by HW)
__device__ __forceinline__ void gload_lds16(const void* g, void* l) {
  __builtin_amdgcn_global_load_lds((const __attribute__((address_space(1))) void*)g,
                                   (__attribute__((address_space(3))) void*)l,
                                   16, 0, 0);
}

// ---------------------------------------------------------------------------
// ONE fp32 -> bf16 convert pass for x, qkv_w, proj_w (saves 2 launches).
// ---------------------------------------------------------------------------
__global__ void cvt_all(const float* __restrict__ x,
                        const float* __restrict__ qw,
                        const float* __restrict__ pw,
                        uint16_t* __restrict__ xd,
                        uint16_t* __restrict__ qd,
                        uint16_t* __restrict__ pd)
{
  const int n4x = NTOK * DIMC / 4;                 // 8388608
  const int n4q = n4x + QKVN * DIMC / 4;           // + 196608
  const int n4t = n4q + DIMC * DIMC / 4;           // + 65536
  int i = blockIdx.x * blockDim.x + threadIdx.x;
  const int stride = gridDim.x * blockDim.x;
  for (; i < n4t; i += stride) {
    const float4* src; ushort4* dst; int j;
    if (i < n4x)      { src = (const float4*)x  + i;         dst = (ushort4*)xd + i;         }
    else if (i < n4q) { j = i - n4x; src = (const float4*)qw + j; dst = (ushort4*)qd + j; }
    else              { j = i - n4q; src = (const float4*)pw + j; dst = (ushort4*)pd + j; }
    const float4 v = *src;
    ushort4 o;
    o.x = f2bf(v.x); o.y = f2bf(v.y); o.z = f2bf(v.z); o.w = f2bf(v.w);
    *dst = o;
  }
}

// ---------------------------------------------------------------------------
// 256x256 8-phase GEMM — round-6 champion, byte-for-byte.
// ---------------------------------------------------------------------------
template <bool OUT_F32>
__global__ __launch_bounds__(512, 2)
void gemm256_8ph(const uint16_t* __restrict__ A,
                 const uint16_t* __restrict__ B,
                 const float* __restrict__ bias,
                 void* __restrict__ Cv,
                 int M, int N, int K, int gx)
{
  __shared__ __align__(16) char lds[131072];

  const int tid = threadIdx.x;
  const int l  = tid & 63, w = tid >> 6;
  const int wm = w >> 2,  wn = w & 3;
  const int lm = l & 15,  lq = l >> 4;

  const int nwg = gridDim.x;
  const int qq = nwg >> 3, rr = nwg & 7;
  const int xcd = blockIdx.x & 7, loc = blockIdx.x >> 3;
  const int sw = (xcd < rr ? xcd * (qq + 1) : rr * (qq + 1) + (xcd - rr) * qq) + loc;
  const long m0 = (long)(sw / gx) * 256;
  const long n0 = (long)(sw % gx) * 256;

  const int srow  = tid >> 3;
  const int scolb = (((tid & 7) ^ (srow & 7)) << 4);
  const uint16_t* Ags = A + (m0 + srow) * (long)K + (scolb >> 1);
  const uint16_t* Bgs = B + (n0 + srow) * (long)K + (scolb >> 1);
  char* ldsW = lds + (w << 10);

#define STAGE(Gs, regionOff, half, kt)                                        \
  {                                                                           \
    const uint16_t* s0_ = (Gs) + (size_t)((half) * 128) * K + (kt);           \
    gload_lds16(s0_,                  ldsW + (regionOff));                    \
    gload_lds16(s0_ + (size_t)64 * K, ldsW + (regionOff) + 8192);             \
  }

  const int colx0 = ((lq ^ (lm & 7)) << 4);
  const int aoff0 = (wm * 64 + lm) * 128 + colx0;
  const int aoff1 = (wm * 64 + lm) * 128 + (colx0 ^ 64);
  const int boff0 = (wn * 32 + lm) * 128 + colx0;
  const int boff1 = (wn * 32 + lm) * 128 + (colx0 ^ 64);

  f32x4  acc[2][2][4][2] = {};
  bf16x8 aX[4][2], aY[4][2];
  bf16x8 b0[2][2], b1[2][2];

#define RD_A(DST, OFF)                                                        \
  _Pragma("unroll") for (int i = 0; i < 4; ++i) {                             \
    DST[i][0] = *(const bf16x8*)(lds + (OFF) + aoff0 + i * 2048);             \
    DST[i][1] = *(const bf16x8*)(lds + (OFF) + aoff1 + i * 2048);             \
  }
#define RD_B(DST, OFF)                                                        \
  _Pragma("unroll") for (int j = 0; j < 2; ++j) {                             \
    DST[j][0] = *(const bf16x8*)(lds + (OFF) + boff0 + j * 2048);             \
    DST[j][1] = *(const bf16x8*)(lds + (OFF) + boff1 + j * 2048);             \
  }
#define MFMA16(AS, BS, QM, QN)                                                \
  __builtin_amdgcn_s_setprio(1);                                              \
  _Pragma("unroll") for (int kk = 0; kk < 2; ++kk)                            \
    _Pragma("unroll") for (int i = 0; i < 4; ++i)                             \
      _Pragma("unroll") for (int j = 0; j < 2; ++j)                           \
        acc[QM][QN][i][j] = __builtin_amdgcn_mfma_f32_16x16x32_bf16(          \
            AS[i][kk], BS[j][kk], acc[QM][QN][i][j], 0, 0, 0);                \
  __builtin_amdgcn_s_setprio(0);
#define VMW(N) asm volatile("s_waitcnt vmcnt(" #N ")" ::: "memory");
#define BAR()  asm volatile("s_barrier" ::: "memory");

  STAGE(Ags, 0,             0, 0)
  STAGE(Bgs, 32768,         0, 0)
  STAGE(Ags, 16384,         1, 0)
  STAGE(Bgs, 49152,         1, 0)
  STAGE(Ags, 65536,         0, 64)
  STAGE(Bgs, 65536 + 32768, 0, 64)
  VMW(8) BAR()
  RD_A(aX, 0) RD_B(b0, 32768)
  VMW(4) BAR()

  for (int t2 = 0; t2 < K / 64; t2 += 2) {
    const int k1 = (t2 + 1) * 64;
    int k2 = (t2 + 2) * 64; if (k2 >= K) k2 = 0;
    int k3 = (t2 + 3) * 64; if (k3 >= K) k3 = 0;

    RD_B(b1, 49152)                 STAGE(Ags, 65536 + 16384, 1, k1)
    MFMA16(aX, b0, 0, 0)            BAR()
    RD_A(aY, 16384)                 STAGE(Bgs, 65536 + 49152, 1, k1)
    MFMA16(aX, b1, 0, 1)            BAR()
    STAGE(Ags, 0, 0, k2)
    MFMA16(aY, b0, 1, 0)            VMW(6) BAR()
    RD_A(aX, 65536) RD_B(b0, 65536 + 32768)
    STAGE(Bgs, 32768, 0, k2)
    MFMA16(aY, b1, 1, 1)            VMW(4) BAR()
    RD_B(b1, 65536 + 49152)         STAGE(Ags, 16384, 1, k2)
    MFMA16(aX, b0, 0, 0)            BAR()
    RD_A(aY, 65536 + 16384)         STAGE(Bgs, 49152, 1, k2)
    MFMA16(aX, b1, 0, 1)            BAR()
    STAGE(Ags, 65536, 0, k3)
    MFMA16(aY, b0, 1, 0)            VMW(6) BAR()
    RD_A(aX, 0) RD_B(b0, 32768)
    STAGE(Bgs, 65536 + 32768, 0, k3)
    MFMA16(aY, b1, 1, 1)            VMW(4) BAR()
  }
#undef STAGE
#undef RD_A
#undef RD_B
#undef MFMA16
#undef VMW
#undef BAR

#pragma unroll
  for (int qm = 0; qm < 2; ++qm)
#pragma unroll
  for (int qn = 0; qn < 2; ++qn)
#pragma unroll
  for (int i = 0; i < 4; ++i)
#pragma unroll
  for (int j = 0; j < 2; ++j) {
    const long m = m0 + qm * 128 + wm * 64 + i * 16 + lq * 4;
    const long n = n0 + qn * 128 + wn * 32 + j * 16 + lm;
    const float bv = bias[n];
#pragma unroll
    for (int r = 0; r < 4; ++r) {
      const float val = acc[qm][qn][i][j][r] + bv;
      if (OUT_F32) ((float*)Cv)[(m + r) * (long)N + n] = val;
      else         ((uint16_t*)Cv)[(m + r) * (long)N + n] = f2bf(val);
    }
  }
}

// ---------------------------------------------------------------------------
// Windowed dilated attention (round-6 math verbatim) + XCD grouping swizzle:
// vb = (rb&7)*512 + (rb>>3) is a bijection on [0,4096) that places the 4
// blocks sharing one group's K/V (192 KB) on the SAME XCD (consecutive vb,
// same rb%8=XCD) -> K/V fetched once per XCD-L2 instead of 4x.
// ---------------------------------------------------------------------------
__global__ void attn_win(const uint16_t* __restrict__ QKV,  // [NTOK][1536] bf16
                         uint16_t* __restrict__ O)          // [NTOK][512]  bf16
{
  __shared__ __align__(16) __bf16 Pl[4][64][72];

  const int tid = threadIdx.x;
  const int l  = tid & 63, w = tid >> 6;
  const int lm = l & 15,  lq = l >> 4;
  const int rb = blockIdx.x;                       // 4096 blocks
  const int vb = (rb & 7) * 512 + (rb >> 3);       // XCD-grouping bijection
  const int g = vb >> 2;
  const int h = (vb & 3) * 4 + w;

  const int d1 = g & 1, d0 = (g >> 1) & 1;
  const int wx = (g >> 2) & 7, wy = (g >> 5) & 7, bb = g >> 8;
  const long tbase = ((long)(bb * 128 + wy * 16 + d0) * 128) + wx * 16 + d1;

  f32x4 invs;
#pragma unroll
  for (int i = 0; i < 4; ++i)
    invs[i] = exp2f(-1.6609640474436813f * (float)((lq & 1) * 4 + i));

  const int co_q = h * HDIM;
  const int co_k = DIMC + h * HDIM;
  const int co_v = 2 * DIMC + h * HDIM;

  bf16x8 qf[4], kf[4];
#pragma unroll
  for (int f = 0; f < 4; ++f) {
    const int n  = f * 16 + lm;
    const int iy = n >> 3, ix = n & 7;
    const float pos = (lq < 2) ? (float)iy : (float)ix;
    const long t = tbase + iy * 256 + ix * 2;
    const uint16_t* qp = QKV + t * QKVN + co_q + lq * 8;
    const uint16_t* kp = QKV + t * QKVN + co_k + lq * 8;
    {
      bf16x8 raw = *(const bf16x8*)qp, o;
#pragma unroll
      for (int i = 0; i < 4; ++i) {
        float x1 = (float)raw[2 * i], x2 = (float)raw[2 * i + 1];
        float s, c; __sincosf(pos * invs[i], &s, &c);
        o[2 * i]     = (__bf16)((x1 * c - x2 * s) * SCALE_F);
        o[2 * i + 1] = (__bf16)((x1 * s + x2 * c) * SCALE_F);
      }
      qf[f] = o;
    }
    {
      bf16x8 raw = *(const bf16x8*)kp, o;
#pragma unroll
      for (int i = 0; i < 4; ++i) {
        float x1 = (float)raw[2 * i], x2 = (float)raw[2 * i + 1];
        float s, c; __sincosf(pos * invs[i], &s, &c);
        o[2 * i]     = (__bf16)(x1 * c - x2 * s);
        o[2 * i + 1] = (__bf16)(x1 * s + x2 * c);
      }
      kf[f] = o;
    }
  }

  const f32x4 fzero = {0.f, 0.f, 0.f, 0.f};
  f32x4 s[4][4];
#pragma unroll
  for (int mi = 0; mi < 4; ++mi)
#pragma unroll
    for (int ni = 0; ni < 4; ++ni)
      s[mi][ni] = __builtin_amdgcn_mfma_f32_16x16x32_bf16(qf[mi], kf[ni], fzero, 0, 0, 0);

  float rsum[4][4];
#pragma unroll
  for (int mi = 0; mi < 4; ++mi)
#pragma unroll
    for (int r = 0; r < 4; ++r) {
      float m = s[mi][0][r];
#pragma unroll
      for (int ni = 1; ni < 4; ++ni) m = fmaxf(m, s[mi][ni][r]);
      m = fmaxf(m, __shfl_xor(m, 1));
      m = fmaxf(m, __shfl_xor(m, 2));
      m = fmaxf(m, __shfl_xor(m, 4));
      m = fmaxf(m, __shfl_xor(m, 8));
      float sum = 0.f;
#pragma unroll
      for (int ni = 0; ni < 4; ++ni) {
        float p = expf(s[mi][ni][r] - m);
        s[mi][ni][r] = p;
        sum += p;
      }
      sum += __shfl_xor(sum, 1);
      sum += __shfl_xor(sum, 2);
      sum += __shfl_xor(sum, 4);
      sum += __shfl_xor(sum, 8);
      rsum[mi][r] = sum;
    }

#pragma unroll
  for (int mi = 0; mi < 4; ++mi)
#pragma unroll
    for (int ni = 0; ni < 4; ++ni)
#pragma unroll
      for (int r = 0; r < 4; ++r)
        Pl[w][mi * 16 + lq * 4 + r][ni * 16 + lm] = (__bf16)s[mi][ni][r];

  bf16x8 pa[4][2];
#pragma unroll
  for (int mi = 0; mi < 4; ++mi)
#pragma unroll
    for (int kk = 0; kk < 2; ++kk)
      pa[mi][kk] = *(const bf16x8*)(&Pl[w][mi * 16 + lm][kk * 32 + lq * 8]);

  bf16x8 vf[2][2];
#pragma unroll
  for (int kk = 0; kk < 2; ++kk)
#pragma unroll
    for (int n2 = 0; n2 < 2; ++n2) {
      const int nb = kk * 32 + lq * 8;
      const long tb2 = tbase + (long)(nb >> 3) * 256;
      const uint16_t* vp = QKV + co_v + n2 * 16 + lm;
      bf16x8 o;
#pragma unroll
      for (int i = 0; i < 8; ++i)
        o[i] = *(const __bf16*)(vp + (tb2 + 2 * i) * QKVN);
      vf[kk][n2] = o;
    }

  f32x4 oacc[4][2] = {};
#pragma unroll
  for (int kk = 0; kk < 2; ++kk)
#pragma unroll
    for (int mi = 0; mi < 4; ++mi)
#pragma unroll
      for (int n2 = 0; n2 < 2; ++n2)
        oacc[mi][n2] = __builtin_amdgcn_mfma_f32_16x16x32_bf16(
            pa[mi][kk], vf[kk][n2], oacc[mi][n2], 0, 0, 0);

#pragma unroll
  for (int mi = 0; mi < 4; ++mi)
#pragma unroll
    for (int r = 0; r < 4; ++r) {
      const int n = mi * 16 + lq * 4 + r;
      const long t = tbase + (n >> 3) * 256 + (n & 7) * 2;
      const float rinv = 1.0f / rsum[mi][r];
#pragma unroll
      for (int n2 = 0; n2 < 2; ++n2)
        O[t * DIMC + h * HDIM + n2 * 16 + lm] = f2bf(oacc[mi][n2][r] * rinv);
    }
}

// ---------------------------------------------------------------------------
extern "C" void kernel_launch(void* const* d_in, const int* in_sizes, int n_in,
                              void* d_out, int out_size, void* d_ws, size_t ws_size,
                              hipStream_t stream)
{
  const float* x      = (const float*)d_in[0];   // [65536][512] fp32
  const float* qkv_w  = (const float*)d_in[1];   // [1536][512]  fp32
  const float* qkv_b  = (const float*)d_in[2];   // [1536]       fp32
  const float* proj_w = (const float*)d_in[3];   // [512][512]   fp32
  const float* proj_b = (const float*)d_in[4];   // [512]        fp32
  float* out = (float*)d_out;                    // [65536][512] fp32

  uint16_t* xb   = (uint16_t*)d_ws;                      // 64 MiB
  uint16_t* qwb  = xb  + (size_t)NTOK * DIMC;            // 1.5 MiB
  uint16_t* pwb  = qwb + (size_t)QKVN * DIMC;            // 0.5 MiB
  uint16_t* qkv  = pwb + (size_t)DIMC * DIMC;            // 192 MiB
  uint16_t* attn = qkv + (size_t)NTOK * QKVN;            // 64 MiB

  // 0) all fp32 -> bf16 conversions in one launch
  cvt_all<<<2048, 256, 0, stream>>>(x, qkv_w, proj_w, xb, qwb, pwb);

  // 1) QKV = x @ qkv_w^T + qkv_b   (bf16 out)
  gemm256_8ph<false><<<dim3((NTOK / 256) * (QKVN / 256)), dim3(512), 0, stream>>>(
      xb, qwb, qkv_b, qkv, NTOK, QKVN, DIMC, QKVN / 256);

  // 2) windowed dilated attention with fused RoPE (XCD-grouped blocks)
  attn_win<<<dim3(1024 * 4), dim3(256), 0, stream>>>(qkv, attn);

  // 3) out = attn @ proj_w^T + proj_b   (fp32 out)
  gemm256_8ph<true><<<dim3((NTOK / 256) * (DIMC / 256)), dim3(512), 0, stream>>>(
      attn, pwb, proj_b, out, NTOK, DIMC, DIMC, DIMC / 256);
}

// Round 14
// 298.375 us; speedup vs baseline: 1.5786x; 1.0029x over previous
//
#include <hip/hip_runtime.h>
#include <hip/hip_bf16.h>
#include <stdint.h>

// ---------------- problem constants ----------------
#define DIMC  512
#define NHEAD 16
#define HDIM  32
#define NTOK  65536          // 4*128*128 tokens
#define QKVN  1536           // 3*DIMC
static constexpr float SCALE_F = 0.17677669529663687f;  // HD^-0.5

typedef __attribute__((ext_vector_type(4))) float  f32x4;
typedef __attribute__((ext_vector_type(8))) __bf16 bf16x8;

__device__ __forceinline__ uint16_t f2bf(float f) {
  union { float f; uint32_t u; } v; v.f = f;
  return (uint16_t)((v.u + 0x7FFFu + ((v.u >> 16) & 1u)) >> 16);
}

// async global->LDS, 16B/lane; LDS dest is wave-uniform base (+lane*16 by HW)
__device__ __forceinline__ void gload_lds16(const void* g, void* l) {
  __builtin_amdgcn_global_load_lds((const __attribute__((address_space(1))) void*)g,
                                   (__attribute__((address_space(3))) void*)l,
                                   16, 0, 0);
}

// ---------------------------------------------------------------------------
// fp32 -> bf16 convert (vectorized, grid-stride). n4 = element count / 4.
// (3 separate launches beat one merged branchy kernel — R13 measured.)
// ---------------------------------------------------------------------------
__global__ void cvt_f32_bf16(const float* __restrict__ src,
                             uint16_t* __restrict__ dst, int n4)
{
  int i = blockIdx.x * blockDim.x + threadIdx.x;
  const int stride = gridDim.x * blockDim.x;
  for (; i < n4; i += stride) {
    const float4 v = ((const float4*)src)[i];
    ushort4 o;
    o.x = f2bf(v.x); o.y = f2bf(v.y); o.z = f2bf(v.z); o.w = f2bf(v.w);
    ((ushort4*)dst)[i] = o;
  }
}

// ---------------------------------------------------------------------------
// 256x256 8-phase GEMM — round-6 champion, byte-for-byte.
// 8 waves (2x4); per-wave 128x64 out over 4 quadrant phases; LDS 128 KiB
// double-buffered; counted vmcnt (never 0 in loop); st_16x32-style XOR
// swizzle via pre-swizzled global source + swizzled ds_read; XCD swizzle.
// ---------------------------------------------------------------------------
template <bool OUT_F32>
__global__ __launch_bounds__(512, 2)
void gemm256_8ph(const uint16_t* __restrict__ A,
                 const uint16_t* __restrict__ B,
                 const float* __restrict__ bias,
                 void* __restrict__ Cv,
                 int M, int N, int K, int gx)
{
  __shared__ __align__(16) char lds[131072];

  const int tid = threadIdx.x;
  const int l  = tid & 63, w = tid >> 6;
  const int wm = w >> 2,  wn = w & 3;
  const int lm = l & 15,  lq = l >> 4;

  const int nwg = gridDim.x;
  const int qq = nwg >> 3, rr = nwg & 7;
  const int xcd = blockIdx.x & 7, loc = blockIdx.x >> 3;
  const int sw = (xcd < rr ? xcd * (qq + 1) : rr * (qq + 1) + (xcd - rr) * qq) + loc;
  const long m0 = (long)(sw / gx) * 256;
  const long n0 = (long)(sw % gx) * 256;

  const int srow  = tid >> 3;
  const int scolb = (((tid & 7) ^ (srow & 7)) << 4);
  const uint16_t* Ags = A + (m0 + srow) * (long)K + (scolb >> 1);
  const uint16_t* Bgs = B + (n0 + srow) * (long)K + (scolb >> 1);
  char* ldsW = lds + (w << 10);

#define STAGE(Gs, regionOff, half, kt)                                        \
  {                                                                           \
    const uint16_t* s0_ = (Gs) + (size_t)((half) * 128) * K + (kt);           \
    gload_lds16(s0_,                  ldsW + (regionOff));                    \
    gload_lds16(s0_ + (size_t)64 * K, ldsW + (regionOff) + 8192);             \
  }

  const int colx0 = ((lq ^ (lm & 7)) << 4);
  const int aoff0 = (wm * 64 + lm) * 128 + colx0;
  const int aoff1 = (wm * 64 + lm) * 128 + (colx0 ^ 64);
  const int boff0 = (wn * 32 + lm) * 128 + colx0;
  const int boff1 = (wn * 32 + lm) * 128 + (colx0 ^ 64);

  f32x4  acc[2][2][4][2] = {};
  bf16x8 aX[4][2], aY[4][2];
  bf16x8 b0[2][2], b1[2][2];

#define RD_A(DST, OFF)                                                        \
  _Pragma("unroll") for (int i = 0; i < 4; ++i) {                             \
    DST[i][0] = *(const bf16x8*)(lds + (OFF) + aoff0 + i * 2048);             \
    DST[i][1] = *(const bf16x8*)(lds + (OFF) + aoff1 + i * 2048);             \
  }
#define RD_B(DST, OFF)                                                        \
  _Pragma("unroll") for (int j = 0; j < 2; ++j) {                             \
    DST[j][0] = *(const bf16x8*)(lds + (OFF) + boff0 + j * 2048);             \
    DST[j][1] = *(const bf16x8*)(lds + (OFF) + boff1 + j * 2048);             \
  }
#define MFMA16(AS, BS, QM, QN)                                                \
  __builtin_amdgcn_s_setprio(1);                                              \
  _Pragma("unroll") for (int kk = 0; kk < 2; ++kk)                            \
    _Pragma("unroll") for (int i = 0; i < 4; ++i)                             \
      _Pragma("unroll") for (int j = 0; j < 2; ++j)                           \
        acc[QM][QN][i][j] = __builtin_amdgcn_mfma_f32_16x16x32_bf16(          \
            AS[i][kk], BS[j][kk], acc[QM][QN][i][j], 0, 0, 0);                \
  __builtin_amdgcn_s_setprio(0);
#define VMW(N) asm volatile("s_waitcnt vmcnt(" #N ")" ::: "memory");
#define BAR()  asm volatile("s_barrier" ::: "memory");

  STAGE(Ags, 0,             0, 0)
  STAGE(Bgs, 32768,         0, 0)
  STAGE(Ags, 16384,         1, 0)
  STAGE(Bgs, 49152,         1, 0)
  STAGE(Ags, 65536,         0, 64)
  STAGE(Bgs, 65536 + 32768, 0, 64)
  VMW(8) BAR()
  RD_A(aX, 0) RD_B(b0, 32768)
  VMW(4) BAR()

  for (int t2 = 0; t2 < K / 64; t2 += 2) {
    const int k1 = (t2 + 1) * 64;
    int k2 = (t2 + 2) * 64; if (k2 >= K) k2 = 0;
    int k3 = (t2 + 3) * 64; if (k3 >= K) k3 = 0;

    RD_B(b1, 49152)                 STAGE(Ags, 65536 + 16384, 1, k1)
    MFMA16(aX, b0, 0, 0)            BAR()
    RD_A(aY, 16384)                 STAGE(Bgs, 65536 + 49152, 1, k1)
    MFMA16(aX, b1, 0, 1)            BAR()
    STAGE(Ags, 0, 0, k2)
    MFMA16(aY, b0, 1, 0)            VMW(6) BAR()
    RD_A(aX, 65536) RD_B(b0, 65536 + 32768)
    STAGE(Bgs, 32768, 0, k2)
    MFMA16(aY, b1, 1, 1)            VMW(4) BAR()
    RD_B(b1, 65536 + 49152)         STAGE(Ags, 16384, 1, k2)
    MFMA16(aX, b0, 0, 0)            BAR()
    RD_A(aY, 65536 + 16384)         STAGE(Bgs, 49152, 1, k2)
    MFMA16(aX, b1, 0, 1)            BAR()
    STAGE(Ags, 65536, 0, k3)
    MFMA16(aY, b0, 1, 0)            VMW(6) BAR()
    RD_A(aX, 0) RD_B(b0, 32768)
    STAGE(Bgs, 65536 + 32768, 0, k3)
    MFMA16(aY, b1, 1, 1)            VMW(4) BAR()
  }
#undef STAGE
#undef RD_A
#undef RD_B
#undef MFMA16
#undef VMW
#undef BAR

#pragma unroll
  for (int qm = 0; qm < 2; ++qm)
#pragma unroll
  for (int qn = 0; qn < 2; ++qn)
#pragma unroll
  for (int i = 0; i < 4; ++i)
#pragma unroll
  for (int j = 0; j < 2; ++j) {
    const long m = m0 + qm * 128 + wm * 64 + i * 16 + lq * 4;
    const long n = n0 + qn * 128 + wn * 32 + j * 16 + lm;
    const float bv = bias[n];
#pragma unroll
    for (int r = 0; r < 4; ++r) {
      const float val = acc[qm][qn][i][j][r] + bv;
      if (OUT_F32) ((float*)Cv)[(m + r) * (long)N + n] = val;
      else         ((uint16_t*)Cv)[(m + r) * (long)N + n] = f2bf(val);
    }
  }
}

// ---------------------------------------------------------------------------
// Windowed dilated attention (round-6 verbatim): one wave per (group, head).
// ---------------------------------------------------------------------------
__global__ void attn_win(const uint16_t* __restrict__ QKV,  // [NTOK][1536] bf16
                         uint16_t* __restrict__ O)          // [NTOK][512]  bf16
{
  __shared__ __align__(16) __bf16 Pl[4][64][72];

  const int tid = threadIdx.x;
  const int l  = tid & 63, w = tid >> 6;
  const int lm = l & 15,  lq = l >> 4;
  const int bid = blockIdx.x;
  const int g = bid >> 2;
  const int h = (bid & 3) * 4 + w;

  const int d1 = g & 1, d0 = (g >> 1) & 1;
  const int wx = (g >> 2) & 7, wy = (g >> 5) & 7, bb = g >> 8;
  const long tbase = ((long)(bb * 128 + wy * 16 + d0) * 128) + wx * 16 + d1;

  f32x4 invs;
#pragma unroll
  for (int i = 0; i < 4; ++i)
    invs[i] = exp2f(-1.6609640474436813f * (float)((lq & 1) * 4 + i));

  const int co_q = h * HDIM;
  const int co_k = DIMC + h * HDIM;
  const int co_v = 2 * DIMC + h * HDIM;

  bf16x8 qf[4], kf[4];
#pragma unroll
  for (int f = 0; f < 4; ++f) {
    const int n  = f * 16 + lm;
    const int iy = n >> 3, ix = n & 7;
    const float pos = (lq < 2) ? (float)iy : (float)ix;
    const long t = tbase + iy * 256 + ix * 2;
    const uint16_t* qp = QKV + t * QKVN + co_q + lq * 8;
    const uint16_t* kp = QKV + t * QKVN + co_k + lq * 8;
    {
      bf16x8 raw = *(const bf16x8*)qp, o;
#pragma unroll
      for (int i = 0; i < 4; ++i) {
        float x1 = (float)raw[2 * i], x2 = (float)raw[2 * i + 1];
        float s, c; __sincosf(pos * invs[i], &s, &c);
        o[2 * i]     = (__bf16)((x1 * c - x2 * s) * SCALE_F);
        o[2 * i + 1] = (__bf16)((x1 * s + x2 * c) * SCALE_F);
      }
      qf[f] = o;
    }
    {
      bf16x8 raw = *(const bf16x8*)kp, o;
#pragma unroll
      for (int i = 0; i < 4; ++i) {
        float x1 = (float)raw[2 * i], x2 = (float)raw[2 * i + 1];
        float s, c; __sincosf(pos * invs[i], &s, &c);
        o[2 * i]     = (__bf16)(x1 * c - x2 * s);
        o[2 * i + 1] = (__bf16)(x1 * s + x2 * c);
      }
      kf[f] = o;
    }
  }

  const f32x4 fzero = {0.f, 0.f, 0.f, 0.f};
  f32x4 s[4][4];
#pragma unroll
  for (int mi = 0; mi < 4; ++mi)
#pragma unroll
    for (int ni = 0; ni < 4; ++ni)
      s[mi][ni] = __builtin_amdgcn_mfma_f32_16x16x32_bf16(qf[mi], kf[ni], fzero, 0, 0, 0);

  float rsum[4][4];
#pragma unroll
  for (int mi = 0; mi < 4; ++mi)
#pragma unroll
    for (int r = 0; r < 4; ++r) {
      float m = s[mi][0][r];
#pragma unroll
      for (int ni = 1; ni < 4; ++ni) m = fmaxf(m, s[mi][ni][r]);
      m = fmaxf(m, __shfl_xor(m, 1));
      m = fmaxf(m, __shfl_xor(m, 2));
      m = fmaxf(m, __shfl_xor(m, 4));
      m = fmaxf(m, __shfl_xor(m, 8));
      float sum = 0.f;
#pragma unroll
      for (int ni = 0; ni < 4; ++ni) {
        float p = expf(s[mi][ni][r] - m);
        s[mi][ni][r] = p;
        sum += p;
      }
      sum += __shfl_xor(sum, 1);
      sum += __shfl_xor(sum, 2);
      sum += __shfl_xor(sum, 4);
      sum += __shfl_xor(sum, 8);
      rsum[mi][r] = sum;
    }

#pragma unroll
  for (int mi = 0; mi < 4; ++mi)
#pragma unroll
    for (int ni = 0; ni < 4; ++ni)
#pragma unroll
      for (int r = 0; r < 4; ++r)
        Pl[w][mi * 16 + lq * 4 + r][ni * 16 + lm] = (__bf16)s[mi][ni][r];

  bf16x8 pa[4][2];
#pragma unroll
  for (int mi = 0; mi < 4; ++mi)
#pragma unroll
    for (int kk = 0; kk < 2; ++kk)
      pa[mi][kk] = *(const bf16x8*)(&Pl[w][mi * 16 + lm][kk * 32 + lq * 8]);

  bf16x8 vf[2][2];
#pragma unroll
  for (int kk = 0; kk < 2; ++kk)
#pragma unroll
    for (int n2 = 0; n2 < 2; ++n2) {
      const int nb = kk * 32 + lq * 8;
      const long tb2 = tbase + (long)(nb >> 3) * 256;
      const uint16_t* vp = QKV + co_v + n2 * 16 + lm;
      bf16x8 o;
#pragma unroll
      for (int i = 0; i < 8; ++i)
        o[i] = *(const __bf16*)(vp + (tb2 + 2 * i) * QKVN);
      vf[kk][n2] = o;
    }

  f32x4 oacc[4][2] = {};
#pragma unroll
  for (int kk = 0; kk < 2; ++kk)
#pragma unroll
    for (int mi = 0; mi < 4; ++mi)
#pragma unroll
      for (int n2 = 0; n2 < 2; ++n2)
        oacc[mi][n2] = __builtin_amdgcn_mfma_f32_16x16x32_bf16(
            pa[mi][kk], vf[kk][n2], oacc[mi][n2], 0, 0, 0);

#pragma unroll
  for (int mi = 0; mi < 4; ++mi)
#pragma unroll
    for (int r = 0; r < 4; ++r) {
      const int n = mi * 16 + lq * 4 + r;
      const long t = tbase + (n >> 3) * 256 + (n & 7) * 2;
      const float rinv = 1.0f / rsum[mi][r];
#pragma unroll
      for (int n2 = 0; n2 < 2; ++n2)
        O[t * DIMC + h * HDIM + n2 * 16 + lm] = f2bf(oacc[mi][n2][r] * rinv);
    }
}

// ---------------------------------------------------------------------------
extern "C" void kernel_launch(void* const* d_in, const int* in_sizes, int n_in,
                              void* d_out, int out_size, void* d_ws, size_t ws_size,
                              hipStream_t stream)
{
  const float* x      = (const float*)d_in[0];   // [65536][512] fp32
  const float* qkv_w  = (const float*)d_in[1];   // [1536][512]  fp32
  const float* qkv_b  = (const float*)d_in[2];   // [1536]       fp32
  const float* proj_w = (const float*)d_in[3];   // [512][512]   fp32
  const float* proj_b = (const float*)d_in[4];   // [512]        fp32
  float* out = (float*)d_out;                    // [65536][512] fp32

  uint16_t* xb   = (uint16_t*)d_ws;                      // 64 MiB
  uint16_t* qwb  = xb  + (size_t)NTOK * DIMC;            // 1.5 MiB
  uint16_t* pwb  = qwb + (size_t)QKVN * DIMC;            // 0.5 MiB
  uint16_t* qkv  = pwb + (size_t)DIMC * DIMC;            // 192 MiB
  uint16_t* attn = qkv + (size_t)NTOK * QKVN;            // 64 MiB

  // 0) fp32 -> bf16 conversions (3 small launches — faster than merged)
  cvt_f32_bf16<<<2048, 256, 0, stream>>>(x,      xb,  NTOK * DIMC / 4);
  cvt_f32_bf16<<<512,  256, 0, stream>>>(qkv_w,  qwb, QKVN * DIMC / 4);
  cvt_f32_bf16<<<256,  256, 0, stream>>>(proj_w, pwb, DIMC * DIMC / 4);

  // 1) QKV = x @ qkv_w^T + qkv_b   (bf16 out)
  gemm256_8ph<false><<<dim3((NTOK / 256) * (QKVN / 256)), dim3(512), 0, stream>>>(
      xb, qwb, qkv_b, qkv, NTOK, QKVN, DIMC, QKVN / 256);

  // 2) windowed dilated attention with fused RoPE (1024 groups x 16 heads)
  attn_win<<<dim3(1024 * 4), dim3(256), 0, stream>>>(qkv, attn);

  // 3) out = attn @ proj_w^T + proj_b   (fp32 out)
  gemm256_8ph<true><<<dim3((NTOK / 256) * (DIMC / 256)), dim3(512), 0, stream>>>(
      attn, pwb, proj_b, out, NTOK, DIMC, DIMC, DIMC / 256);
}